// Round 2
// baseline (31.140 us; speedup 1.0000x reference)
//
#include <hip/hip_runtime.h>

#define CC 512
#define CK 256
#define BB 8
#define TT 1024

__device__ __forceinline__ float wave_allreduce(float v) {
#pragma unroll
    for (int m = 1; m < 64; m <<= 1)
        v += __shfl_xor(v, m, 64);
    return v;
}

// K1: three independent jobs in one dispatch.
//  blocks [0,256)   : L1 = proj_w @ out_w            (512x512 GEMM, K=512, 32x32 tiles)
//  blocks [256,384) : v1[b,c] = Wv[c,:]@cond[b,:]+bv (4096 rows, 4 waves x 8 rows)
//  blocks [384,512) : t[c] = proj_w[c,:]@out_b + proj_b[c] (512 rows, 1 row/wave)
__global__ void k1_kernel(const float* __restrict__ P, const float* __restrict__ O,
                          const float* __restrict__ Wv, const float* __restrict__ bv,
                          const float* __restrict__ ob, const float* __restrict__ pb,
                          const float* __restrict__ cond,
                          float* __restrict__ L1, float* __restrict__ t,
                          float* __restrict__ v1) {
    const int blk = blockIdx.x;
    const int tid = threadIdx.x;
    const int wave = tid >> 6, lane = tid & 63;

    if (blk < 256) {
        __shared__ float As[32][33];
        __shared__ float Bs[32][33];
        const int ti = (blk >> 4) * 32, tj = (blk & 15) * 32;
        const int lrow = tid >> 3, lc4 = (tid & 7) * 4;
        const int ty = tid >> 4, tx = tid & 15;
        float a00 = 0.f, a01 = 0.f, a10 = 0.f, a11 = 0.f;
        for (int k = 0; k < 512; k += 32) {
            __syncthreads();
            *(float4*)&As[lrow][lc4] = *(const float4*)&P[(ti + lrow) * 512 + k + lc4];
            *(float4*)&Bs[lrow][lc4] = *(const float4*)&O[(k + lrow) * 512 + tj + lc4];
            __syncthreads();
#pragma unroll
            for (int kk = 0; kk < 32; ++kk) {
                const float x0 = As[2 * ty][kk], x1 = As[2 * ty + 1][kk];
                const float y0 = Bs[kk][2 * tx], y1 = Bs[kk][2 * tx + 1];
                a00 += x0 * y0; a01 += x0 * y1; a10 += x1 * y0; a11 += x1 * y1;
            }
        }
        float* d = L1 + (ti + 2 * ty) * 512 + tj + 2 * tx;
        d[0] = a00; d[1] = a01; d[512] = a10; d[513] = a11;
    } else if (blk < 384) {
        const int gw = (blk - 256) * 4 + wave;   // 512 waves, 8 rows each
#pragma unroll
        for (int r = 0; r < 8; ++r) {
            const int o = gw * 8 + r;            // o in [0,4096)
            const int b = o >> 9, c = o & 511;
            float acc = 0.f;
#pragma unroll
            for (int j = 0; j < CK; j += 64)
                acc += Wv[c * CK + j + lane] * cond[b * CK + j + lane];
            acc = wave_allreduce(acc);
            if (lane == 0) v1[o] = acc + bv[c];
        }
    } else {
        const int c = (blk - 384) * 4 + wave;    // 512 waves, 1 row each
        float acc = 0.f;
#pragma unroll
        for (int k = 0; k < CC; k += 64)
            acc += P[c * CC + k + lane] * ob[k + lane];
        acc = wave_allreduce(acc);
        if (lane == 0) t[c] = acc + pb[c];
    }
}

// K2: v2[b,c] = wv2[c,:]@v1[b,:] + b2[c]   (4096 rows; 256 blocks x 4 waves x 4 rows)
__global__ void k2_kernel(const float* __restrict__ wv2, const float* __restrict__ b2,
                          const float* __restrict__ v1, float* __restrict__ v2) {
    const int wave = threadIdx.x >> 6, lane = threadIdx.x & 63;
    const int gw = blockIdx.x * 4 + wave;
#pragma unroll
    for (int r = 0; r < 4; ++r) {
        const int o = gw * 4 + r;
        const int b = o >> 9, c = o & 511;
        float acc = 0.f;
#pragma unroll
        for (int j = 0; j < CC; j += 64)
            acc += wv2[c * CC + j + lane] * v1[b * CC + j + lane];
        acc = wave_allreduce(acc);
        if (lane == 0) v2[o] = acc + b2[c];
    }
}

// K3: per (b,c) row: w = L1[c,:]@v2[b,:] + t[c];  out[b,c,:] = x[b,c,:] + w
// 1024 blocks x 4 waves = 4096 rows; each wave streams its 4 KB row as float4.
__global__ void k3_kernel(const float* __restrict__ L1, const float* __restrict__ t,
                          const float* __restrict__ v2, const float* __restrict__ x,
                          float* __restrict__ out) {
    const int wave = threadIdx.x >> 6, lane = threadIdx.x & 63;
    const int o = blockIdx.x * 4 + wave;         // row index in [0,4096)
    const int b = o >> 9, c = o & 511;
    float acc = 0.f;
#pragma unroll
    for (int j = 0; j < CC; j += 64)
        acc += L1[c * CC + j + lane] * v2[b * CC + j + lane];
    const float w = wave_allreduce(acc) + t[c];  // all lanes hold w

    const float4* x4 = (const float4*)x + (size_t)o * (TT / 4);
    float4* o4 = (float4*)out + (size_t)o * (TT / 4);
#pragma unroll
    for (int i = 0; i < TT / 4; i += 64) {
        float4 v = x4[i + lane];
        v.x += w; v.y += w; v.z += w; v.w += w;
        o4[i + lane] = v;
    }
}

extern "C" void kernel_launch(void* const* d_in, const int* in_sizes, int n_in,
                              void* d_out, int out_size, void* d_ws, size_t ws_size,
                              hipStream_t stream) {
    const float* x         = (const float*)d_in[0];
    const float* cond      = (const float*)d_in[1];
    const float* Wv        = (const float*)d_in[8];
    const float* bv        = (const float*)d_in[9];
    const float* in_proj_w = (const float*)d_in[10];
    const float* in_proj_b = (const float*)d_in[11];
    const float* out_w     = (const float*)d_in[12];
    const float* out_b     = (const float*)d_in[13];
    const float* proj_w    = (const float*)d_in[14];
    const float* proj_b    = (const float*)d_in[15];
    float* out = (float*)d_out;

    float* L1 = (float*)d_ws;             // 512*512 floats = 1 MB
    float* t  = L1 + CC * CC;             // 512
    float* v1 = t + CC;                   // 4096
    float* v2 = v1 + BB * CC;             // 4096

    k1_kernel<<<512, 256, 0, stream>>>(proj_w, out_w, Wv, bv, out_b, proj_b,
                                       cond, L1, t, v1);
    k2_kernel<<<256, 256, 0, stream>>>(in_proj_w + 2 * CC * CC, in_proj_b + 2 * CC,
                                       v1, v2);
    k3_kernel<<<1024, 256, 0, stream>>>(L1, t, v2, x, out);
}